// Round 7
// baseline (180.560 us; speedup 1.0000x reference)
//
#include <hip/hip_runtime.h>
#include <hip/hip_bf16.h>

typedef unsigned short u16;
typedef __attribute__((ext_vector_type(8))) unsigned short u16x8;
typedef __attribute__((ext_vector_type(4))) float f32x4;

#define TPB 128
// ws layout: ints ws[0..9]=counts, ws[15]=isbf16, ws[16+e*1024+j]=atom lists.
// Tables at byte 65536: per (e,c) slot of 9312 floats:
//   A3 [q][p][i3] at +0 (8704), A2 [q][p] at +8704 (544), A1 [q][i] at +9248 (64)
#define TBL_OFF 65536
#define SLOT 9312
#define TBL_BYTES ((size_t)1280 * SLOT * 4)
#define PART_OFF (TBL_OFF + TBL_BYTES)
#define PART_BYTES ((size_t)4 * 1024 * 512 * 4)
#define WS_NEEDED_OLD (TBL_OFF + TBL_BYTES)
#define WS_NEEDED_NEW (PART_OFF + PART_BYTES)

__device__ __forceinline__ float bf2f(u16 v){
  union { unsigned int u; float f; } x; x.u = ((unsigned int)v) << 16; return x.f;
}
__device__ __forceinline__ u16 f2bf(float f){
  union { float f; unsigned int u; } x; x.f = f;
  unsigned int u = x.u;
  u += 0x7FFFu + ((u >> 16) & 1u);   // round-to-nearest-even
  return (u16)(u >> 16);
}
__device__ __forceinline__ float ld(const void* p, int idx, int isbf){
  return isbf ? bf2f(((const u16*)p)[idx]) : ((const float*)p)[idx];
}

// ============ kernel 1: dtype detect + parallel species lists ================
__global__ void k_classify2(const void* __restrict__ nav, int* __restrict__ ws){
  __shared__ int scnt[10];
  __shared__ int sf[16];
  __shared__ int sflag;
  const int b = threadIdx.x;  // 1024 threads
  if (b < 10) scnt[b] = 0;

  // bf16 one-hot at even index -> word 0x00003F80 (never a valid f32 here)
  const unsigned int* w = (const unsigned int*)nav;
  int found = 0;
  for (int i = b; i < 5120; i += 1024) found |= (w[i] == 0x00003F80u);
  unsigned long long m = __ballot(found);
  if ((b & 63) == 0) sf[b >> 6] = (m != 0ULL);
  __syncthreads();
  if (b == 0){ int f = 0; for (int i = 0; i < 16; i++) f |= sf[i]; sflag = f; ws[15] = f; }
  __syncthreads();
  const int isbf = sflag;

  int e = 0;
  #pragma unroll
  for (int j = 0; j < 10; j++){
    if (ld(nav, b*10 + j, isbf) > 0.5f) e = j;
  }
  int pos = atomicAdd(&scnt[e], 1);   // order-independent outputs -> list order free
  ws[16 + e*1024 + pos] = b;
  __syncthreads();
  if (b < 10) ws[b] = scnt[b];
}

// ============ kernel B: build tables; W staged in LDS ========================
// grid (73 jtiles, 16 cgroups, 10 e), block 128
__global__ __launch_bounds__(128) void k_build3(
    const void* __restrict__ U3_0, const void* __restrict__ U2_0, const void* __restrict__ U1_0,
    const void* __restrict__ W3_0, const void* __restrict__ W2_0, const void* __restrict__ W1_0,
    const void* __restrict__ U3_1, const void* __restrict__ U2_1, const void* __restrict__ U1_1,
    const void* __restrict__ W3_1, const void* __restrict__ W2_1, const void* __restrict__ W1_1,
    const int* __restrict__ ws, float* __restrict__ tb)
{
  const int jt = blockIdx.x, cg = blockIdx.y, e = blockIdx.z;
  const int j  = jt*128 + threadIdx.x;
  const int isbf = ws[15];
  const int c0 = cg*8;

  // W slots: 0-4 W3_0 | 5-11 W3_1 | 12-13 W2_0 | 14-16 W2_1 | 17 W1_0 | 18 W1_1
  __shared__ float sW[19*8];
  for (int idx = threadIdx.x; idx < 152; idx += 128){   // STRIDED: 152 > blockDim!
    const int slot = idx >> 3, cc = idx & 7;
    const int c = c0 + cc;
    float v;
    if      (slot < 5)  v = ld(W3_0, (e*5 + slot)*128 + c, isbf);
    else if (slot < 12) v = ld(W3_1, (e*7 + slot - 5)*128 + c, isbf);
    else if (slot < 14) v = ld(W2_0, (e*2 + slot - 12)*128 + c, isbf);
    else if (slot < 17) v = ld(W2_1, (e*3 + slot - 14)*128 + c, isbf);
    else if (slot == 17) v = ld(W1_0, e*128 + c, isbf);
    else                 v = ld(W1_1, e*128 + c, isbf);
    sW[slot*8 + cc] = v;
  }
  __syncthreads();
  if (j >= 9312) return;

  float u[7];
  int K, slot0, dst;

  if (j < 8704){
    const int q = j / 2176, rem = j % 2176;
    const int p = rem >> 4, i3 = rem & 15;
    int i1 = 0, rr = p;
    while (rr >= 16 - i1){ rr -= 16 - i1; i1++; }
    const int i2 = i1 + rr;
    if (q == 0){
      K = 5; slot0 = 0;
      const int a  = (i1*256 + i2*16 + i3)*5;
      const int bb = (i2*256 + i1*16 + i3)*5;
      #pragma unroll
      for (int k = 0; k < 5; k++){
        float v = ld(U3_0, a + k, isbf);
        if (i1 != i2) v += ld(U3_0, bb + k, isbf);
        u[k] = v;
      }
    } else {
      K = 7; slot0 = 5;
      const int mm = q - 1;
      const int a  = (mm*4096 + i1*256 + i2*16 + i3)*7;
      const int bb = (mm*4096 + i2*256 + i1*16 + i3)*7;
      #pragma unroll
      for (int k = 0; k < 7; k++){
        float v = ld(U3_1, a + k, isbf);
        if (i1 != i2) v += ld(U3_1, bb + k, isbf);
        u[k] = v;
      }
    }
    dst = j;
  } else if (j < 9248){
    const int jj = j - 8704;            // 0..543
    const int q = jj / 136, p = jj % 136;
    int i1 = 0, rr = p;
    while (rr >= 16 - i1){ rr -= 16 - i1; i1++; }
    const int i2 = i1 + rr;
    if (q == 0){
      K = 2; slot0 = 12;
      const int a = (i1*16 + i2)*2, bb = (i2*16 + i1)*2;
      #pragma unroll
      for (int k = 0; k < 2; k++){
        float v = ld(U2_0, a + k, isbf);
        if (i1 != i2) v += ld(U2_0, bb + k, isbf);
        u[k] = v;
      }
    } else {
      K = 3; slot0 = 14;
      const int mm = q - 1;
      const int a = (mm*256 + i1*16 + i2)*3, bb = (mm*256 + i2*16 + i1)*3;
      #pragma unroll
      for (int k = 0; k < 3; k++){
        float v = ld(U2_1, a + k, isbf);
        if (i1 != i2) v += ld(U2_1, bb + k, isbf);
        u[k] = v;
      }
    }
    dst = 8704 + jj;
  } else {
    const int jj = j - 9248;            // 0..63
    const int q = jj >> 4, i = jj & 15;
    K = 1;
    if (q == 0){ slot0 = 17; u[0] = ld(U1_0, i, isbf); }
    else       { slot0 = 18; u[0] = ld(U1_1, (q - 1)*16 + i, isbf); }
    dst = 9248 + jj;
  }

  #pragma unroll
  for (int cc = 0; cc < 8; cc++){
    float v = 0.f;
    for (int k = 0; k < K; k++) v += u[k] * sW[(slot0 + k)*8 + cc];
    tb[(size_t)(e*128 + c0 + cc)*SLOT + dst] = v;
  }
}

// ============ kernel C: contract, LDS-staged table chunk =====================
// grid (1280, 4); partials to part[pc][b][c*4+q]
__global__ __launch_bounds__(TPB) void k_contract4(
    const void* __restrict__ a_i, const int* __restrict__ ws,
    const float* __restrict__ tb, float* __restrict__ part)
{
  const int e   = blockIdx.x >> 7;
  const int c   = blockIdx.x & 127;
  const int pc  = blockIdx.y;
  const int tid = threadIdx.x;
  const int isbf  = ws[15];
  const int count = ws[e];
  const int* lst  = ws + 16 + e*1024;
  const float* __restrict__ base = tb + (size_t)(e*128 + c)*SLOT;
  if (count == 0) return;

  __shared__ __align__(16) float sT[4*544];    // A3 chunk [q][34][16]
  __shared__ __align__(16) float sA2s[136];    // A2 chunk [n][q] (b128-readable)
  __shared__ __align__(16) float sA1s[64];     // A1 [i][q]
  __shared__ unsigned char sI1s[34], sI2s[34];
  __shared__ float sX[TPB][17];                // per-thread x (stride 17: conflict-free)

  const int p0 = pc*34;

  // ---- stage table chunk (coalesced vector loads, once per block) ----
  for (int v = tid; v < 544; v += TPB){        // A3: 4 q-sections of 544 floats
    const int q = v / 136, u = v - q*136;
    *(f32x4*)&sT[q*544 + u*4] = *(const f32x4*)&base[q*2176 + p0*16 + u*4];
  }
  for (int idx = tid; idx < 136; idx += TPB){  // A2 -> [n][q]
    const int n = idx >> 2, q = idx & 3;
    sA2s[idx] = base[8704 + q*136 + p0 + n];
  }
  if (tid < 64){                               // A1 -> [i][q]
    const int i = tid >> 2, q = tid & 3;
    sA1s[tid] = base[9248 + q*16 + i];
  }
  if (tid < 34){
    int p = p0 + tid, i1 = 0, rem = p;
    while (rem >= 16 - i1){ rem -= 16 - i1; i1++; }
    sI1s[tid] = (unsigned char)i1;
    sI2s[tid] = (unsigned char)(i1 + rem);
  }
  __syncthreads();

  // ---- atom loop ----
  for (int t0 = 0; t0 < count; t0 += TPB){
    int t = t0 + tid;
    const bool act = t < count;
    if (!act) t = count - 1;          // clamp: recompute same atom, discard
    const int b = lst[t];
    const int xbase = (b*128 + c)*16;

    float xr[16];
    if (isbf){
      const u16* xp = (const u16*)a_i + xbase;
      u16x8 v0 = *(const u16x8*)(xp);
      u16x8 v1 = *(const u16x8*)(xp + 8);
      #pragma unroll
      for (int i = 0; i < 8; i++){ xr[i] = bf2f(v0[i]); xr[8 + i] = bf2f(v1[i]); }
    } else {
      const float* xp = (const float*)a_i + xbase;
      f32x4 v0 = *(const f32x4*)(xp);
      f32x4 v1 = *(const f32x4*)(xp + 4);
      f32x4 v2 = *(const f32x4*)(xp + 8);
      f32x4 v3 = *(const f32x4*)(xp + 12);
      #pragma unroll
      for (int i = 0; i < 4; i++){
        xr[i] = v0[i]; xr[4+i] = v1[i]; xr[8+i] = v2[i]; xr[12+i] = v3[i];
      }
    }
    #pragma unroll
    for (int i = 0; i < 16; i++) sX[tid][i] = xr[i];

    float r0 = 0.f, r1 = 0.f, r2 = 0.f, r3 = 0.f;

    #pragma unroll 2
    for (int n = 0; n < 34; ++n){
      const int i1 = sI1s[n], i2 = sI2s[n];
      const float xx = sX[tid][i1] * sX[tid][i2];
      f32x4 sa = *(const f32x4*)&sA2s[n*4];
      float s0 = sa[0], s1 = sa[1], s2 = sa[2], s3 = sa[3];
      const float* a0 = &sT[n*16];
      #pragma unroll
      for (int i3 = 0; i3 < 16; ++i3){
        const float xv = xr[i3];
        s0 += a0[       i3]*xv;
        s1 += a0[544  + i3]*xv;
        s2 += a0[1088 + i3]*xv;
        s3 += a0[1632 + i3]*xv;
      }
      r0 += s0*xx; r1 += s1*xx; r2 += s2*xx; r3 += s3*xx;
    }

    if (pc == 3){
      #pragma unroll
      for (int i = 0; i < 16; i++){
        f32x4 sa = *(const f32x4*)&sA1s[i*4];
        const float xv = xr[i];
        r0 += sa[0]*xv; r1 += sa[1]*xv; r2 += sa[2]*xv; r3 += sa[3]*xv;
      }
    }

    if (act){
      f32x4 v; v[0] = r0; v[1] = r1; v[2] = r2; v[3] = r3;
      *(f32x4*)(part + ((size_t)(pc*1024 + b)*512 + c*4)) = v;
    }
  }
}

// ============ kernel D: combine partials + convert ===========================
__global__ __launch_bounds__(128) void k_combine(
    const float* __restrict__ part, const int* __restrict__ ws, void* __restrict__ outv)
{
  const int b = blockIdx.x, c = threadIdx.x;
  const int isbf = ws[15];
  f32x4 r;
  r[0] = 0.f; r[1] = 0.f; r[2] = 0.f; r[3] = 0.f;
  #pragma unroll
  for (int pc = 0; pc < 4; pc++){
    f32x4 v = *(const f32x4*)(part + ((size_t)(pc*1024 + b)*512 + c*4));
    r[0] += v[0]; r[1] += v[1]; r[2] += v[2]; r[3] += v[3];
  }
  if (isbf){
    u16* ob = (u16*)outv + (size_t)b*512;
    ob[c]             = f2bf(r[0]);
    ob[128 + c*3 + 0] = f2bf(r[1]);
    ob[128 + c*3 + 1] = f2bf(r[2]);
    ob[128 + c*3 + 2] = f2bf(r[3]);
  } else {
    float* ob = (float*)outv + (size_t)b*512;
    ob[c]             = r[0];
    ob[128 + c*3 + 0] = r[1];
    ob[128 + c*3 + 1] = r[2];
    ob[128 + c*3 + 2] = r[3];
  }
}

// ===================== fallback kernels (rounds 3/4, verified) ===============
__global__ __launch_bounds__(256) void k_build(
    const void* __restrict__ U3_0, const void* __restrict__ U2_0, const void* __restrict__ U1_0,
    const void* __restrict__ W3_0, const void* __restrict__ W2_0, const void* __restrict__ W1_0,
    const void* __restrict__ U3_1, const void* __restrict__ U2_1, const void* __restrict__ U1_1,
    const void* __restrict__ W3_1, const void* __restrict__ W2_1, const void* __restrict__ W1_1,
    const int* __restrict__ ws, float* __restrict__ tb)
{
  const int eq = blockIdx.y;
  const int e  = eq >> 2, q = eq & 3;
  const int bx = blockIdx.x;
  const int jt = bx >> 5, ct = bx & 31;
  const int j  = jt*64 + (threadIdx.x & 63);
  const int c  = ct*4 + (threadIdx.x >> 6);
  const int isbf = ws[15];
  if (j >= 2328) return;

  float* base = tb + (size_t)(e*128 + c)*SLOT;

  if (j < 2176){
    const int p = j >> 4, i3 = j & 15;
    int i1 = 0, rem = p;
    while (rem >= 16 - i1){ rem -= 16 - i1; i1++; }
    const int i2 = i1 + rem;
    float v = 0.f;
    if (q == 0){
      const int a  = (i1*256 + i2*16 + i3)*5;
      const int bb = (i2*256 + i1*16 + i3)*5;
      #pragma unroll
      for (int k = 0; k < 5; k++){
        float u = ld(U3_0, a + k, isbf);
        if (i1 != i2) u += ld(U3_0, bb + k, isbf);
        v += u * ld(W3_0, (e*5 + k)*128 + c, isbf);
      }
    } else {
      const int m  = q - 1;
      const int a  = (m*4096 + i1*256 + i2*16 + i3)*7;
      const int bb = (m*4096 + i2*256 + i1*16 + i3)*7;
      #pragma unroll
      for (int k = 0; k < 7; k++){
        float u = ld(U3_1, a + k, isbf);
        if (i1 != i2) u += ld(U3_1, bb + k, isbf);
        v += u * ld(W3_1, (e*7 + k)*128 + c, isbf);
      }
    }
    base[q*2176 + j] = v;
  } else if (j < 2312){
    const int p = j - 2176;
    int i1 = 0, rem = p;
    while (rem >= 16 - i1){ rem -= 16 - i1; i1++; }
    const int i2 = i1 + rem;
    float v = 0.f;
    if (q == 0){
      const int a = (i1*16 + i2)*2, bb = (i2*16 + i1)*2;
      #pragma unroll
      for (int k = 0; k < 2; k++){
        float u = ld(U2_0, a + k, isbf);
        if (i1 != i2) u += ld(U2_0, bb + k, isbf);
        v += u * ld(W2_0, (e*2 + k)*128 + c, isbf);
      }
    } else {
      const int m = q - 1;
      const int a = (m*256 + i1*16 + i2)*3, bb = (m*256 + i2*16 + i1)*3;
      #pragma unroll
      for (int k = 0; k < 3; k++){
        float u = ld(U2_1, a + k, isbf);
        if (i1 != i2) u += ld(U2_1, bb + k, isbf);
        v += u * ld(W2_1, (e*3 + k)*128 + c, isbf);
      }
    }
    base[8704 + q*136 + p] = v;
  } else {
    const int i = j - 2312;
    float v = (q == 0) ? ld(U1_0, i, isbf) * ld(W1_0, e*128 + c, isbf)
                       : ld(U1_1, (q - 1)*16 + i, isbf) * ld(W1_1, e*128 + c, isbf);
    base[9248 + q*16 + i] = v;
  }
}

__global__ __launch_bounds__(TPB) void k_contract2(
    const void* __restrict__ a_i, const int* __restrict__ ws,
    const float* __restrict__ tb, void* __restrict__ outv)
{
  const int e   = blockIdx.x >> 7;
  const int c   = blockIdx.x & 127;
  const int tid = threadIdx.x;
  const int isbf  = ws[15];
  const int count = ws[e];
  const int* lst  = ws + 16 + e*1024;
  const float* __restrict__ base = tb + (size_t)(e*128 + c)*SLOT;

  __shared__ float sX[TPB][17];

  for (int t0 = 0; t0 < count; t0 += TPB){
    int t = t0 + tid;
    const bool act = t < count;
    if (!act) t = count - 1;
    const int b = lst[t];
    const int xbase = (b*128 + c)*16;

    float xr[16];
    if (isbf){
      const u16* xp = (const u16*)a_i + xbase;
      u16x8 v0 = *(const u16x8*)(xp);
      u16x8 v1 = *(const u16x8*)(xp + 8);
      #pragma unroll
      for (int i = 0; i < 8; i++){ xr[i] = bf2f(v0[i]); xr[8 + i] = bf2f(v1[i]); }
    } else {
      const float* xp = (const float*)a_i + xbase;
      f32x4 v0 = *(const f32x4*)(xp);
      f32x4 v1 = *(const f32x4*)(xp + 4);
      f32x4 v2 = *(const f32x4*)(xp + 8);
      f32x4 v3 = *(const f32x4*)(xp + 12);
      #pragma unroll
      for (int i = 0; i < 4; i++){
        xr[i] = v0[i]; xr[4+i] = v1[i]; xr[8+i] = v2[i]; xr[12+i] = v3[i];
      }
    }
    #pragma unroll
    for (int i = 0; i < 16; i++) sX[tid][i] = xr[i];

    float r0 = 0.f, r1 = 0.f, r2 = 0.f, r3 = 0.f;
    const float* pA3 = base;
    const float* pA2 = base + 8704;

    #pragma clang loop unroll(disable)
    for (int i1 = 0; i1 < 16; ++i1){
      const float x1 = sX[tid][i1];
      #pragma clang loop unroll(disable)
      for (int i2 = i1; i2 < 16; ++i2){
        const float xx = x1 * sX[tid][i2];
        float s0 = pA2[0], s1 = pA2[136], s2 = pA2[272], s3 = pA2[408];
        #pragma unroll
        for (int i3 = 0; i3 < 16; ++i3){
          const float xv = xr[i3];
          s0 += pA3[        i3]*xv;
          s1 += pA3[2176 + i3]*xv;
          s2 += pA3[4352 + i3]*xv;
          s3 += pA3[6528 + i3]*xv;
        }
        r0 += s0*xx; r1 += s1*xx; r2 += s2*xx; r3 += s3*xx;
        pA3 += 16; pA2 += 1;
      }
    }
    #pragma unroll
    for (int i = 0; i < 16; i++){
      const float xv = xr[i];
      r0 += base[9248 + i]*xv;
      r1 += base[9264 + i]*xv;
      r2 += base[9280 + i]*xv;
      r3 += base[9296 + i]*xv;
    }

    if (act){
      if (isbf){
        u16* ob = (u16*)outv + (size_t)b*512;
        ob[c]             = f2bf(r0);
        ob[128 + c*3 + 0] = f2bf(r1);
        ob[128 + c*3 + 1] = f2bf(r2);
        ob[128 + c*3 + 2] = f2bf(r3);
      } else {
        float* ob = (float*)outv + (size_t)b*512;
        ob[c]             = r0;
        ob[128 + c*3 + 0] = r1;
        ob[128 + c*3 + 1] = r2;
        ob[128 + c*3 + 2] = r3;
      }
    }
  }
}

__global__ __launch_bounds__(TPB) void k_contract(
    const void* __restrict__ a_i,
    const void* __restrict__ U3_0, const void* __restrict__ U2_0, const void* __restrict__ U1_0,
    const void* __restrict__ W3_0, const void* __restrict__ W2_0, const void* __restrict__ W1_0,
    const void* __restrict__ U3_1, const void* __restrict__ U2_1, const void* __restrict__ U1_1,
    const void* __restrict__ W3_1, const void* __restrict__ W2_1, const void* __restrict__ W1_1,
    const int* __restrict__ ws, void* __restrict__ outv)
{
  const int bx  = blockIdx.x;
  const int e   = bx >> 7;
  const int c   = bx & 127;
  const int tid = threadIdx.x;
  const int isbf = ws[15];

  __shared__ float sA3[4*136*16];
  __shared__ float sA2[4*136];
  __shared__ float sA1[4*16];
  __shared__ unsigned char sI1[136], sI2[136];
  __shared__ float sX[TPB][17];

  for (int p = tid; p < 136; p += TPB){
    int i1 = 0, rem = p;
    while (rem >= 16 - i1){ rem -= 16 - i1; i1++; }
    sI1[p] = (unsigned char)i1;
    sI2[p] = (unsigned char)(i1 + rem);
  }

  float w3_0[5], w2_0[2], w3_1[7], w2_1[3];
  #pragma unroll
  for (int k = 0; k < 5; k++) w3_0[k] = ld(W3_0, (e*5 + k)*128 + c, isbf);
  #pragma unroll
  for (int k = 0; k < 2; k++) w2_0[k] = ld(W2_0, (e*2 + k)*128 + c, isbf);
  const float w1_0 = ld(W1_0, e*128 + c, isbf);
  #pragma unroll
  for (int k = 0; k < 7; k++) w3_1[k] = ld(W3_1, (e*7 + k)*128 + c, isbf);
  #pragma unroll
  for (int k = 0; k < 3; k++) w2_1[k] = ld(W2_1, (e*3 + k)*128 + c, isbf);
  const float w1_1 = ld(W1_1, e*128 + c, isbf);

  __syncthreads();

  for (int q = 0; q < 4; q++){
    for (int idx = tid; idx < 136*16; idx += TPB){
      const int p  = idx >> 4;
      const int i3 = idx & 15;
      const int i1 = sI1[p], i2 = sI2[p];
      float v = 0.f;
      if (q == 0){
        const int a  = (i1*256 + i2*16 + i3)*5;
        const int bb = (i2*256 + i1*16 + i3)*5;
        #pragma unroll
        for (int k = 0; k < 5; k++){
          float u = ld(U3_0, a + k, isbf);
          if (i1 != i2) u += ld(U3_0, bb + k, isbf);
          v += u * w3_0[k];
        }
      } else {
        const int m  = q - 1;
        const int a  = (m*4096 + i1*256 + i2*16 + i3)*7;
        const int bb = (m*4096 + i2*256 + i1*16 + i3)*7;
        #pragma unroll
        for (int k = 0; k < 7; k++){
          float u = ld(U3_1, a + k, isbf);
          if (i1 != i2) u += ld(U3_1, bb + k, isbf);
          v += u * w3_1[k];
        }
      }
      sA3[q*2176 + idx] = v;
    }
  }
  for (int idx = tid; idx < 4*136; idx += TPB){
    const int q = idx / 136, p = idx - q*136;
    const int i1 = sI1[p], i2 = sI2[p];
    float v = 0.f;
    if (q == 0){
      const int a = (i1*16 + i2)*2, bb = (i2*16 + i1)*2;
      #pragma unroll
      for (int k = 0; k < 2; k++){
        float u = ld(U2_0, a + k, isbf);
        if (i1 != i2) u += ld(U2_0, bb + k, isbf);
        v += u * w2_0[k];
      }
    } else {
      const int m = q - 1;
      const int a = (m*256 + i1*16 + i2)*3, bb = (m*256 + i2*16 + i1)*3;
      #pragma unroll
      for (int k = 0; k < 3; k++){
        float u = ld(U2_1, a + k, isbf);
        if (i1 != i2) u += ld(U2_1, bb + k, isbf);
        v += u * w2_1[k];
      }
    }
    sA2[idx] = v;
  }
  if (tid < 64){
    const int q = tid >> 4, i1 = tid & 15;
    sA1[tid] = (q == 0) ? ld(U1_0, i1, isbf) * w1_0
                        : ld(U1_1, (q - 1)*16 + i1, isbf) * w1_1;
  }
  __syncthreads();

  const int count = ws[e];
  const int* lst  = ws + 16 + e*1024;

  for (int t = tid; t < count; t += TPB){
    const int b = lst[t];
    const int xbase = (b*128 + c)*16;

    float xr[16];
    if (isbf){
      const u16* xp = (const u16*)a_i + xbase;
      u16x8 v0 = *(const u16x8*)(xp);
      u16x8 v1 = *(const u16x8*)(xp + 8);
      #pragma unroll
      for (int i = 0; i < 8; i++){ xr[i] = bf2f(v0[i]); xr[8 + i] = bf2f(v1[i]); }
    } else {
      const float* xp = (const float*)a_i + xbase;
      f32x4 v0 = *(const f32x4*)(xp);
      f32x4 v1 = *(const f32x4*)(xp + 4);
      f32x4 v2 = *(const f32x4*)(xp + 8);
      f32x4 v3 = *(const f32x4*)(xp + 12);
      #pragma unroll
      for (int i = 0; i < 4; i++){
        xr[i] = v0[i]; xr[4+i] = v1[i]; xr[8+i] = v2[i]; xr[12+i] = v3[i];
      }
    }
    #pragma unroll
    for (int i = 0; i < 16; i++) sX[tid][i] = xr[i];

    float r0 = 0.f, r1 = 0.f, r2 = 0.f, r3 = 0.f;
    int p = 0;
    for (int i1 = 0; i1 < 16; i1++){
      const float x1 = sX[tid][i1];
      for (int i2 = i1; i2 < 16; i2++, p++){
        const float* a0 = &sA3[(0*136 + p)*16];
        const float* a1 = &sA3[(1*136 + p)*16];
        const float* a2 = &sA3[(2*136 + p)*16];
        const float* a3 = &sA3[(3*136 + p)*16];
        float s0 = sA2[        p];
        float s1 = sA2[136   + p];
        float s2 = sA2[272   + p];
        float s3 = sA2[408   + p];
        #pragma unroll
        for (int i3 = 0; i3 < 16; i3++){
          const float xv = xr[i3];
          s0 += a0[i3]*xv;
          s1 += a1[i3]*xv;
          s2 += a2[i3]*xv;
          s3 += a3[i3]*xv;
        }
        const float xx = x1 * sX[tid][i2];
        r0 += s0*xx; r1 += s1*xx; r2 += s2*xx; r3 += s3*xx;
      }
    }
    #pragma unroll
    for (int i1 = 0; i1 < 16; i1++){
      const float xv = xr[i1];
      r0 += sA1[     i1]*xv;
      r1 += sA1[16 + i1]*xv;
      r2 += sA1[32 + i1]*xv;
      r3 += sA1[48 + i1]*xv;
    }

    if (isbf){
      u16* ob = (u16*)outv + (size_t)b*512;
      ob[c]             = f2bf(r0);
      ob[128 + c*3 + 0] = f2bf(r1);
      ob[128 + c*3 + 1] = f2bf(r2);
      ob[128 + c*3 + 2] = f2bf(r3);
    } else {
      float* ob = (float*)outv + (size_t)b*512;
      ob[c]             = r0;
      ob[128 + c*3 + 0] = r1;
      ob[128 + c*3 + 1] = r2;
      ob[128 + c*3 + 2] = r3;
    }
  }
}

extern "C" void kernel_launch(void* const* d_in, const int* in_sizes, int n_in,
                              void* d_out, int out_size, void* d_ws, size_t ws_size,
                              hipStream_t stream) {
  int* ws = (int*)d_ws;
  hipLaunchKernelGGL(k_classify2, dim3(1), dim3(1024), 0, stream, d_in[1], ws);

  if (ws_size >= WS_NEEDED_NEW){
    float* tb   = (float*)((char*)d_ws + TBL_OFF);
    float* part = (float*)((char*)d_ws + PART_OFF);
    hipLaunchKernelGGL(k_build3, dim3(73, 16, 10), dim3(128), 0, stream,
                       d_in[2], d_in[3], d_in[4], d_in[5], d_in[6], d_in[7],
                       d_in[8], d_in[9], d_in[10], d_in[11], d_in[12], d_in[13],
                       ws, tb);
    hipLaunchKernelGGL(k_contract4, dim3(1280, 4), dim3(TPB), 0, stream,
                       d_in[0], ws, tb, part);
    hipLaunchKernelGGL(k_combine, dim3(1024), dim3(128), 0, stream,
                       part, ws, d_out);
  } else if (ws_size >= WS_NEEDED_OLD){
    float* tb = (float*)((char*)d_ws + TBL_OFF);
    hipLaunchKernelGGL(k_build, dim3(37*32, 40), dim3(256), 0, stream,
                       d_in[2], d_in[3], d_in[4], d_in[5], d_in[6], d_in[7],
                       d_in[8], d_in[9], d_in[10], d_in[11], d_in[12], d_in[13],
                       ws, tb);
    hipLaunchKernelGGL(k_contract2, dim3(1280), dim3(TPB), 0, stream,
                       d_in[0], ws, tb, d_out);
  } else {
    hipLaunchKernelGGL(k_contract, dim3(1280), dim3(TPB), 0, stream,
                       d_in[0],
                       d_in[2], d_in[3], d_in[4], d_in[5], d_in[6], d_in[7],
                       d_in[8], d_in[9], d_in[10], d_in[11], d_in[12], d_in[13],
                       ws, d_out);
  }
}

// Round 8
// 165.748 us; speedup vs baseline: 1.0894x; 1.0894x over previous
//
#include <hip/hip_runtime.h>
#include <hip/hip_bf16.h>

typedef unsigned short u16;
typedef __attribute__((ext_vector_type(8))) unsigned short u16x8;
typedef __attribute__((ext_vector_type(8))) short bf16x8;   // MFMA A/B frag (8 bf16)
typedef __attribute__((ext_vector_type(4))) float f32x4;

#define TPB 128
// ws layout: ints ws[0..9]=counts, ws[15]=isbf16, ws[16+e*1024+j]=atom lists.
// TBL region (byte 65536):
//   bf16 path: frag table ftb[(e*128+c)*36 + t][lane 0..63][8 bf16]  (47.2 MB)
//   f32  path: per (e,c) SLOT of 9312 f32 (A3/A2/A1)                 (47.7 MB)
#define TBL_OFF 65536
#define SLOT 9312
#define TBL_BYTES ((size_t)1280 * SLOT * 4)
#define PART_OFF (TBL_OFF + TBL_BYTES)
#define PART_BYTES ((size_t)4 * 1024 * 512 * 4)
#define WS_NEEDED_NEW (PART_OFF + PART_BYTES)

__device__ __forceinline__ float bf2f(u16 v){
  union { unsigned int u; float f; } x; x.u = ((unsigned int)v) << 16; return x.f;
}
__device__ __forceinline__ u16 f2bf(float f){
  union { float f; unsigned int u; } x; x.f = f;
  unsigned int u = x.u;
  u += 0x7FFFu + ((u >> 16) & 1u);   // round-to-nearest-even
  return (u16)(u >> 16);
}
__device__ __forceinline__ float ld(const void* p, int idx, int isbf){
  return isbf ? bf2f(((const u16*)p)[idx]) : ((const float*)p)[idx];
}

// ============ kernel 1: dtype detect + parallel species lists ================
__global__ void k_classify2(const void* __restrict__ nav, int* __restrict__ ws){
  __shared__ int scnt[10];
  __shared__ int sf[16];
  __shared__ int sflag;
  const int b = threadIdx.x;  // 1024 threads
  if (b < 10) scnt[b] = 0;

  // bf16 one-hot at even index -> word 0x00003F80 (never a valid f32 here)
  const unsigned int* w = (const unsigned int*)nav;
  int found = 0;
  for (int i = b; i < 5120; i += 1024) found |= (w[i] == 0x00003F80u);
  unsigned long long m = __ballot(found);
  if ((b & 63) == 0) sf[b >> 6] = (m != 0ULL);
  __syncthreads();
  if (b == 0){ int f = 0; for (int i = 0; i < 16; i++) f |= sf[i]; sflag = f; ws[15] = f; }
  __syncthreads();
  const int isbf = sflag;

  int e = 0;
  #pragma unroll
  for (int j = 0; j < 10; j++){
    if (ld(nav, b*10 + j, isbf) > 0.5f) e = j;
  }
  int pos = atomicAdd(&scnt[e], 1);   // order-independent outputs -> list order free
  ws[16 + e*1024 + pos] = b;
  __syncthreads();
  if (b < 10) ws[b] = scnt[b];
}

// ============ kernel BF: build A-fragment table (bf16 path only) =============
// A3ext rows: [q][p]: p<136 = folded-sym A3 (k<16) + A2 at k=16; p==136 = A1;
// p 137..143 = 0.  Tile t = q*9 + pb covers rows pb*16..pb*16+15, cols k.
// Lane l of tile t holds row (l&15), k = (l>>4)*8 + j  (j=0..7).
// grid (36 t, 8 cgroups of 16, 10 e), block 64 (1 wave)
__global__ __launch_bounds__(64) void k_buildF(
    const void* __restrict__ U3_0, const void* __restrict__ U2_0, const void* __restrict__ U1_0,
    const void* __restrict__ W3_0, const void* __restrict__ W2_0, const void* __restrict__ W1_0,
    const void* __restrict__ U3_1, const void* __restrict__ U2_1, const void* __restrict__ U1_1,
    const void* __restrict__ W3_1, const void* __restrict__ W2_1, const void* __restrict__ W1_1,
    const int* __restrict__ ws, u16* __restrict__ ftb)
{
  if (!ws[15]) return;               // bf16 inputs only
  const int t  = blockIdx.x;         // 0..35
  const int cg = blockIdx.y;         // 0..7
  const int e  = blockIdx.z;         // 0..9
  const int q  = t / 9, pb = t % 9;
  const int lane = threadIdx.x;
  const int g = lane >> 4, row = lane & 15;
  const int p = pb*16 + row;
  const int c0 = cg*16;

  // W slots: 0-4 W3_0 | 5-11 W3_1 | 12-13 W2_0 | 14-16 W2_1 | 17 W1_0 | 18 W1_1
  __shared__ float sW[19*16];
  for (int idx = lane; idx < 304; idx += 64){   // strided: 304 > blockDim
    const int slot = idx >> 4, cc = idx & 15;
    const int c = c0 + cc;
    float v;
    if      (slot < 5)  v = bf2f(((const u16*)W3_0)[(e*5 + slot)*128 + c]);
    else if (slot < 12) v = bf2f(((const u16*)W3_1)[(e*7 + slot - 5)*128 + c]);
    else if (slot < 14) v = bf2f(((const u16*)W2_0)[(e*2 + slot - 12)*128 + c]);
    else if (slot < 17) v = bf2f(((const u16*)W2_1)[(e*3 + slot - 14)*128 + c]);
    else if (slot == 17) v = bf2f(((const u16*)W1_0)[e*128 + c]);
    else                 v = bf2f(((const u16*)W1_1)[e*128 + c]);
    sW[slot*16 + cc] = v;
  }
  __syncthreads();

  float u[8][7];
  #pragma unroll
  for (int j = 0; j < 8; j++)
    #pragma unroll
    for (int k = 0; k < 7; k++) u[j][k] = 0.f;
  int K = 0, slot0 = 0;

  if (p < 136){
    int i1 = 0, rem = p;
    while (rem >= 16 - i1){ rem -= 16 - i1; i1++; }
    const int i2 = i1 + rem;
    if (g < 2){
      if (q == 0){
        K = 5; slot0 = 0;
        #pragma unroll
        for (int j = 0; j < 8; j++){
          const int i3 = g*8 + j;
          const int a  = (i1*256 + i2*16 + i3)*5;
          const int bb = (i2*256 + i1*16 + i3)*5;
          #pragma unroll
          for (int k = 0; k < 5; k++){
            float v = bf2f(((const u16*)U3_0)[a + k]);
            if (i1 != i2) v += bf2f(((const u16*)U3_0)[bb + k]);
            u[j][k] = v;
          }
        }
      } else {
        K = 7; slot0 = 5;
        const int mm = q - 1;
        #pragma unroll
        for (int j = 0; j < 8; j++){
          const int i3 = g*8 + j;
          const int a  = (mm*4096 + i1*256 + i2*16 + i3)*7;
          const int bb = (mm*4096 + i2*256 + i1*16 + i3)*7;
          #pragma unroll
          for (int k = 0; k < 7; k++){
            float v = bf2f(((const u16*)U3_1)[a + k]);
            if (i1 != i2) v += bf2f(((const u16*)U3_1)[bb + k]);
            u[j][k] = v;
          }
        }
      }
    } else if (g == 2){
      // k=16 column (j==0): A2 value; j>0 stay 0
      if (q == 0){
        K = 2; slot0 = 12;
        const int a = (i1*16 + i2)*2, bb = (i2*16 + i1)*2;
        #pragma unroll
        for (int k = 0; k < 2; k++){
          float v = bf2f(((const u16*)U2_0)[a + k]);
          if (i1 != i2) v += bf2f(((const u16*)U2_0)[bb + k]);
          u[0][k] = v;
        }
      } else {
        K = 3; slot0 = 14;
        const int mm = q - 1;
        const int a = (mm*256 + i1*16 + i2)*3, bb = (mm*256 + i2*16 + i1)*3;
        #pragma unroll
        for (int k = 0; k < 3; k++){
          float v = bf2f(((const u16*)U2_1)[a + k]);
          if (i1 != i2) v += bf2f(((const u16*)U2_1)[bb + k]);
          u[0][k] = v;
        }
      }
    }
    // g==3: zeros
  } else if (p == 136 && g < 2){
    K = 1; slot0 = (q == 0) ? 17 : 18;
    #pragma unroll
    for (int j = 0; j < 8; j++){
      const int i = g*8 + j;
      u[j][0] = (q == 0) ? bf2f(((const u16*)U1_0)[i])
                         : bf2f(((const u16*)U1_1)[(q - 1)*16 + i]);
    }
  }
  // p>136 or (p==136, g>=2): zeros

  for (int cc = 0; cc < 16; cc++){
    u16x8 o;
    #pragma unroll
    for (int j = 0; j < 8; j++){
      float v = 0.f;
      #pragma unroll
      for (int k = 0; k < 7; k++)
        if (k < K) v += u[j][k] * sW[(slot0 + k)*16 + cc];
      o[j] = f2bf(v);
    }
    u16* dst = ftb + ((size_t)((e*128 + c0 + cc)*36 + t))*512 + lane*8;
    *(u16x8*)dst = o;
  }
}

// ============ kernel MF: MFMA contraction (bf16 path only) ===================
// grid (1280 ec, 2 halves), block 64 (1 wave). A-frags in registers.
__global__ __launch_bounds__(64) void k_contract_mfma(
    const u16* __restrict__ a_i, const int* __restrict__ ws,
    const u16* __restrict__ ftb, u16* __restrict__ out)
{
  if (!ws[15]) return;
  const int e = blockIdx.x >> 7, c = blockIdx.x & 127;
  const int half = blockIdx.y;
  const int lane = threadIdx.x;
  const int count = ws[e];
  if (count == 0) return;
  const int ngroups = (count + 15) >> 4;
  const int* lst = ws + 16 + e*1024;
  const int col = lane & 15, g = lane >> 4;

  __shared__ float sx[16][20];   // per-atom-col x (f32), [16]=1.0, [17..19]=0
  __shared__ int   sip[144];     // p -> i1 | i2<<8

  for (int p = lane; p < 144; p += 64){
    int i1, i2;
    if (p < 136){ int a = 0, rem = p; while (rem >= 16 - a){ rem -= 16 - a; a++; } i1 = a; i2 = a + rem; }
    else if (p == 136){ i1 = 16; i2 = 16; }   // M=1 (A1 row)
    else { i1 = 17; i2 = 17; }                // M=0 (pad rows)
    sip[p] = i1 | (i2 << 8);
  }
  if (lane < 16){ sx[lane][16] = 1.f; sx[lane][17] = 0.f; sx[lane][18] = 0.f; sx[lane][19] = 0.f; }
  __syncthreads();

  // load all 36 A-frags (one-time, held in VGPRs)
  bf16x8 af[36];
  const u16* fb = ftb + (size_t)(e*128 + c)*36*512 + lane*8;
  #pragma unroll
  for (int t = 0; t < 36; t++) af[t] = *(const bf16x8*)(fb + t*512);

  for (int grp = half; grp < ngroups; grp += 2){
    const int aidx = grp*16 + col;
    const bool act = aidx < count;
    const int b = lst[act ? aidx : count - 1];   // clamp, store-masked

    // B-frag: col = atom, k = g*8+j.  g0/g1: x bf16 direct from global;
    // g2: k=16 -> 1.0 (A2 bias col); g3: 0
    bf16x8 bfr;
    if (g < 2){
      bfr = *(const bf16x8*)(a_i + (size_t)(b*128 + c)*16 + g*8);
    } else if (g == 2){
      bfr = (bf16x8){(short)0x3F80, 0,0,0,0,0,0,0};
    } else {
      bfr = (bf16x8){0,0,0,0,0,0,0,0};
    }
    // stage this group's x as f32 for monomial build
    if (g < 2){
      #pragma unroll
      for (int j = 0; j < 8; j++) sx[col][g*8 + j] = bf2f((u16)bfr[j]);
    }
    __syncthreads();

    // monomials for my rows: p = pb*16 + g*4 + r
    float m[9][4];
    #pragma unroll
    for (int pb = 0; pb < 9; pb++)
      #pragma unroll
      for (int r = 0; r < 4; r++){
        const int ip = sip[pb*16 + g*4 + r];
        m[pb][r] = sx[col][ip & 0xff] * sx[col][ip >> 8];
      }

    float racc[4];
    #pragma unroll
    for (int q = 0; q < 4; q++){
      float rq = 0.f;
      #pragma unroll
      for (int pb = 0; pb < 9; pb++){
        f32x4 acc = {0.f, 0.f, 0.f, 0.f};
        acc = __builtin_amdgcn_mfma_f32_16x16x32_bf16(af[q*9 + pb], bfr, acc, 0, 0, 0);
        rq += m[pb][0]*acc[0] + m[pb][1]*acc[1] + m[pb][2]*acc[2] + m[pb][3]*acc[3];
      }
      racc[q] = rq;
    }
    // reduce partial-p over the 4 lane groups
    #pragma unroll
    for (int q = 0; q < 4; q++){
      racc[q] += __shfl_xor(racc[q], 16);
      racc[q] += __shfl_xor(racc[q], 32);
    }
    if (act && g == 0){
      u16* ob = out + (size_t)b*512;
      ob[c]             = f2bf(racc[0]);
      ob[128 + c*3 + 0] = f2bf(racc[1]);
      ob[128 + c*3 + 1] = f2bf(racc[2]);
      ob[128 + c*3 + 2] = f2bf(racc[3]);
    }
    __syncthreads();   // protect sx before next group's overwrite
  }
}

// ===================== f32-input fallback pipeline (gated on !isbf) ==========
__global__ __launch_bounds__(128) void k_build3(
    const void* __restrict__ U3_0, const void* __restrict__ U2_0, const void* __restrict__ U1_0,
    const void* __restrict__ W3_0, const void* __restrict__ W2_0, const void* __restrict__ W1_0,
    const void* __restrict__ U3_1, const void* __restrict__ U2_1, const void* __restrict__ U1_1,
    const void* __restrict__ W3_1, const void* __restrict__ W2_1, const void* __restrict__ W1_1,
    const int* __restrict__ ws, float* __restrict__ tb)
{
  const int isbf = ws[15];
  if (isbf) return;                       // f32 path only
  const int jt = blockIdx.x, cg = blockIdx.y, e = blockIdx.z;
  const int j  = jt*128 + threadIdx.x;
  const int c0 = cg*8;

  __shared__ float sW[19*8];
  for (int idx = threadIdx.x; idx < 152; idx += 128){
    const int slot = idx >> 3, cc = idx & 7;
    const int c = c0 + cc;
    float v;
    if      (slot < 5)  v = ld(W3_0, (e*5 + slot)*128 + c, 0);
    else if (slot < 12) v = ld(W3_1, (e*7 + slot - 5)*128 + c, 0);
    else if (slot < 14) v = ld(W2_0, (e*2 + slot - 12)*128 + c, 0);
    else if (slot < 17) v = ld(W2_1, (e*3 + slot - 14)*128 + c, 0);
    else if (slot == 17) v = ld(W1_0, e*128 + c, 0);
    else                 v = ld(W1_1, e*128 + c, 0);
    sW[slot*8 + cc] = v;
  }
  __syncthreads();
  if (j >= 9312) return;

  float u[7];
  int K, slot0, dst;

  if (j < 8704){
    const int q = j / 2176, rem = j % 2176;
    const int p = rem >> 4, i3 = rem & 15;
    int i1 = 0, rr = p;
    while (rr >= 16 - i1){ rr -= 16 - i1; i1++; }
    const int i2 = i1 + rr;
    if (q == 0){
      K = 5; slot0 = 0;
      const int a  = (i1*256 + i2*16 + i3)*5;
      const int bb = (i2*256 + i1*16 + i3)*5;
      #pragma unroll
      for (int k = 0; k < 5; k++){
        float v = ld(U3_0, a + k, 0);
        if (i1 != i2) v += ld(U3_0, bb + k, 0);
        u[k] = v;
      }
    } else {
      K = 7; slot0 = 5;
      const int mm = q - 1;
      const int a  = (mm*4096 + i1*256 + i2*16 + i3)*7;
      const int bb = (mm*4096 + i2*256 + i1*16 + i3)*7;
      #pragma unroll
      for (int k = 0; k < 7; k++){
        float v = ld(U3_1, a + k, 0);
        if (i1 != i2) v += ld(U3_1, bb + k, 0);
        u[k] = v;
      }
    }
    dst = j;
  } else if (j < 9248){
    const int jj = j - 8704;
    const int q = jj / 136, p = jj % 136;
    int i1 = 0, rr = p;
    while (rr >= 16 - i1){ rr -= 16 - i1; i1++; }
    const int i2 = i1 + rr;
    if (q == 0){
      K = 2; slot0 = 12;
      const int a = (i1*16 + i2)*2, bb = (i2*16 + i1)*2;
      #pragma unroll
      for (int k = 0; k < 2; k++){
        float v = ld(U2_0, a + k, 0);
        if (i1 != i2) v += ld(U2_0, bb + k, 0);
        u[k] = v;
      }
    } else {
      K = 3; slot0 = 14;
      const int mm = q - 1;
      const int a = (mm*256 + i1*16 + i2)*3, bb = (mm*256 + i2*16 + i1)*3;
      #pragma unroll
      for (int k = 0; k < 3; k++){
        float v = ld(U2_1, a + k, 0);
        if (i1 != i2) v += ld(U2_1, bb + k, 0);
        u[k] = v;
      }
    }
    dst = 8704 + jj;
  } else {
    const int jj = j - 9248;
    const int q = jj >> 4, i = jj & 15;
    K = 1;
    if (q == 0){ slot0 = 17; u[0] = ld(U1_0, i, 0); }
    else       { slot0 = 18; u[0] = ld(U1_1, (q - 1)*16 + i, 0); }
    dst = 9248 + jj;
  }

  #pragma unroll
  for (int cc = 0; cc < 8; cc++){
    float v = 0.f;
    for (int k = 0; k < K; k++) v += u[k] * sW[(slot0 + k)*8 + cc];
    tb[(size_t)(e*128 + c0 + cc)*SLOT + dst] = v;
  }
}

__global__ __launch_bounds__(TPB) void k_contract3(
    const void* __restrict__ a_i, const int* __restrict__ ws,
    const float* __restrict__ tb, float* __restrict__ part)
{
  if (ws[15]) return;                     // f32 path only
  const int e   = blockIdx.x >> 7;
  const int c   = blockIdx.x & 127;
  const int pc  = blockIdx.y;
  const int tid = threadIdx.x;
  const int count = ws[e];
  const int* lst  = ws + 16 + e*1024;
  const float* __restrict__ base = tb + (size_t)(e*128 + c)*SLOT;
  if (count == 0) return;

  __shared__ float sX[TPB][17];
  const int p0 = pc*34;

  for (int t0 = 0; t0 < count; t0 += TPB){
    int t = t0 + tid;
    const bool act = t < count;
    if (!act) t = count - 1;
    const int b = lst[t];
    const int xbase = (b*128 + c)*16;

    float xr[16];
    {
      const float* xp = (const float*)a_i + xbase;
      f32x4 v0 = *(const f32x4*)(xp);
      f32x4 v1 = *(const f32x4*)(xp + 4);
      f32x4 v2 = *(const f32x4*)(xp + 8);
      f32x4 v3 = *(const f32x4*)(xp + 12);
      #pragma unroll
      for (int i = 0; i < 4; i++){
        xr[i] = v0[i]; xr[4+i] = v1[i]; xr[8+i] = v2[i]; xr[12+i] = v3[i];
      }
    }
    #pragma unroll
    for (int i = 0; i < 16; i++) sX[tid][i] = xr[i];

    float r0 = 0.f, r1 = 0.f, r2 = 0.f, r3 = 0.f;
    const float* pA3 = base + p0*16;
    const float* pA2 = base + 8704 + p0;
    int i1 = 0, rm = p0;
    while (rm >= 16 - i1){ rm -= 16 - i1; i1++; }
    int i2 = i1 + rm;

    #pragma clang loop unroll(disable)
    for (int n = 0; n < 34; ++n){
      const float xx = sX[tid][i1] * sX[tid][i2];
      float s0 = pA2[0], s1 = pA2[136], s2 = pA2[272], s3 = pA2[408];
      #pragma unroll
      for (int i3 = 0; i3 < 16; ++i3){
        const float xv = xr[i3];
        s0 += pA3[        i3]*xv;
        s1 += pA3[2176 + i3]*xv;
        s2 += pA3[4352 + i3]*xv;
        s3 += pA3[6528 + i3]*xv;
      }
      r0 += s0*xx; r1 += s1*xx; r2 += s2*xx; r3 += s3*xx;
      pA3 += 16; pA2 += 1;
      i2++; if (i2 == 16){ i1++; i2 = i1; }
    }

    if (pc == 3){
      #pragma unroll
      for (int i = 0; i < 16; i++){
        const float xv = xr[i];
        r0 += base[9248 + i]*xv;
        r1 += base[9264 + i]*xv;
        r2 += base[9280 + i]*xv;
        r3 += base[9296 + i]*xv;
      }
    }

    if (act){
      f32x4 v; v[0] = r0; v[1] = r1; v[2] = r2; v[3] = r3;
      *(f32x4*)(part + ((size_t)(pc*1024 + b)*512 + c*4)) = v;
    }
  }
}

__global__ __launch_bounds__(128) void k_combine(
    const float* __restrict__ part, const int* __restrict__ ws, void* __restrict__ outv)
{
  if (ws[15]) return;                     // f32 path only (bf16 path writes out directly)
  const int b = blockIdx.x, c = threadIdx.x;
  f32x4 r; r[0] = 0.f; r[1] = 0.f; r[2] = 0.f; r[3] = 0.f;
  #pragma unroll
  for (int pc = 0; pc < 4; pc++){
    f32x4 v = *(const f32x4*)(part + ((size_t)(pc*1024 + b)*512 + c*4));
    r[0] += v[0]; r[1] += v[1]; r[2] += v[2]; r[3] += v[3];
  }
  float* ob = (float*)outv + (size_t)b*512;
  ob[c]             = r[0];
  ob[128 + c*3 + 0] = r[1];
  ob[128 + c*3 + 1] = r[2];
  ob[128 + c*3 + 2] = r[3];
}

// ===================== tiny-ws fallback (round-3, verified, both dtypes) =====
__global__ __launch_bounds__(TPB) void k_contract(
    const void* __restrict__ a_i,
    const void* __restrict__ U3_0, const void* __restrict__ U2_0, const void* __restrict__ U1_0,
    const void* __restrict__ W3_0, const void* __restrict__ W2_0, const void* __restrict__ W1_0,
    const void* __restrict__ U3_1, const void* __restrict__ U2_1, const void* __restrict__ U1_1,
    const void* __restrict__ W3_1, const void* __restrict__ W2_1, const void* __restrict__ W1_1,
    const int* __restrict__ ws, void* __restrict__ outv)
{
  const int bx  = blockIdx.x;
  const int e   = bx >> 7;
  const int c   = bx & 127;
  const int tid = threadIdx.x;
  const int isbf = ws[15];

  __shared__ float sA3[4*136*16];
  __shared__ float sA2[4*136];
  __shared__ float sA1[4*16];
  __shared__ unsigned char sI1[136], sI2[136];
  __shared__ float sX[TPB][17];

  for (int p = tid; p < 136; p += TPB){
    int i1 = 0, rem = p;
    while (rem >= 16 - i1){ rem -= 16 - i1; i1++; }
    sI1[p] = (unsigned char)i1;
    sI2[p] = (unsigned char)(i1 + rem);
  }

  float w3_0[5], w2_0[2], w3_1[7], w2_1[3];
  #pragma unroll
  for (int k = 0; k < 5; k++) w3_0[k] = ld(W3_0, (e*5 + k)*128 + c, isbf);
  #pragma unroll
  for (int k = 0; k < 2; k++) w2_0[k] = ld(W2_0, (e*2 + k)*128 + c, isbf);
  const float w1_0 = ld(W1_0, e*128 + c, isbf);
  #pragma unroll
  for (int k = 0; k < 7; k++) w3_1[k] = ld(W3_1, (e*7 + k)*128 + c, isbf);
  #pragma unroll
  for (int k = 0; k < 3; k++) w2_1[k] = ld(W2_1, (e*3 + k)*128 + c, isbf);
  const float w1_1 = ld(W1_1, e*128 + c, isbf);

  __syncthreads();

  for (int q = 0; q < 4; q++){
    for (int idx = tid; idx < 136*16; idx += TPB){
      const int p  = idx >> 4;
      const int i3 = idx & 15;
      const int i1 = sI1[p], i2 = sI2[p];
      float v = 0.f;
      if (q == 0){
        const int a  = (i1*256 + i2*16 + i3)*5;
        const int bb = (i2*256 + i1*16 + i3)*5;
        #pragma unroll
        for (int k = 0; k < 5; k++){
          float u = ld(U3_0, a + k, isbf);
          if (i1 != i2) u += ld(U3_0, bb + k, isbf);
          v += u * w3_0[k];
        }
      } else {
        const int m  = q - 1;
        const int a  = (m*4096 + i1*256 + i2*16 + i3)*7;
        const int bb = (m*4096 + i2*256 + i1*16 + i3)*7;
        #pragma unroll
        for (int k = 0; k < 7; k++){
          float u = ld(U3_1, a + k, isbf);
          if (i1 != i2) u += ld(U3_1, bb + k, isbf);
          v += u * w3_1[k];
        }
      }
      sA3[q*2176 + idx] = v;
    }
  }
  for (int idx = tid; idx < 4*136; idx += TPB){
    const int q = idx / 136, p = idx - q*136;
    const int i1 = sI1[p], i2 = sI2[p];
    float v = 0.f;
    if (q == 0){
      const int a = (i1*16 + i2)*2, bb = (i2*16 + i1)*2;
      #pragma unroll
      for (int k = 0; k < 2; k++){
        float u = ld(U2_0, a + k, isbf);
        if (i1 != i2) u += ld(U2_0, bb + k, isbf);
        v += u * w2_0[k];
      }
    } else {
      const int m = q - 1;
      const int a = (m*256 + i1*16 + i2)*3, bb = (m*256 + i2*16 + i1)*3;
      #pragma unroll
      for (int k = 0; k < 3; k++){
        float u = ld(U2_1, a + k, isbf);
        if (i1 != i2) u += ld(U2_1, bb + k, isbf);
        v += u * w2_1[k];
      }
    }
    sA2[idx] = v;
  }
  if (tid < 64){
    const int q = tid >> 4, i1 = tid & 15;
    sA1[tid] = (q == 0) ? ld(U1_0, i1, isbf) * w1_0
                        : ld(U1_1, (q - 1)*16 + i1, isbf) * w1_1;
  }
  __syncthreads();

  const int count = ws[e];
  const int* lst  = ws + 16 + e*1024;

  for (int t = tid; t < count; t += TPB){
    const int b = lst[t];
    const int xbase = (b*128 + c)*16;

    float xr[16];
    if (isbf){
      const u16* xp = (const u16*)a_i + xbase;
      u16x8 v0 = *(const u16x8*)(xp);
      u16x8 v1 = *(const u16x8*)(xp + 8);
      #pragma unroll
      for (int i = 0; i < 8; i++){ xr[i] = bf2f(v0[i]); xr[8 + i] = bf2f(v1[i]); }
    } else {
      const float* xp = (const float*)a_i + xbase;
      f32x4 v0 = *(const f32x4*)(xp);
      f32x4 v1 = *(const f32x4*)(xp + 4);
      f32x4 v2 = *(const f32x4*)(xp + 8);
      f32x4 v3 = *(const f32x4*)(xp + 12);
      #pragma unroll
      for (int i = 0; i < 4; i++){
        xr[i] = v0[i]; xr[4+i] = v1[i]; xr[8+i] = v2[i]; xr[12+i] = v3[i];
      }
    }
    #pragma unroll
    for (int i = 0; i < 16; i++) sX[tid][i] = xr[i];

    float r0 = 0.f, r1 = 0.f, r2 = 0.f, r3 = 0.f;
    int p = 0;
    for (int i1 = 0; i1 < 16; i1++){
      const float x1 = sX[tid][i1];
      for (int i2 = i1; i2 < 16; i2++, p++){
        const float* a0 = &sA3[(0*136 + p)*16];
        const float* a1 = &sA3[(1*136 + p)*16];
        const float* a2 = &sA3[(2*136 + p)*16];
        const float* a3 = &sA3[(3*136 + p)*16];
        float s0 = sA2[        p];
        float s1 = sA2[136   + p];
        float s2 = sA2[272   + p];
        float s3 = sA2[408   + p];
        #pragma unroll
        for (int i3 = 0; i3 < 16; i3++){
          const float xv = xr[i3];
          s0 += a0[i3]*xv;
          s1 += a1[i3]*xv;
          s2 += a2[i3]*xv;
          s3 += a3[i3]*xv;
        }
        const float xx = x1 * sX[tid][i2];
        r0 += s0*xx; r1 += s1*xx; r2 += s2*xx; r3 += s3*xx;
      }
    }
    #pragma unroll
    for (int i1 = 0; i1 < 16; i1++){
      const float xv = xr[i1];
      r0 += sA1[     i1]*xv;
      r1 += sA1[16 + i1]*xv;
      r2 += sA1[32 + i1]*xv;
      r3 += sA1[48 + i1]*xv;
    }

    if (isbf){
      u16* ob = (u16*)outv + (size_t)b*512;
      ob[c]             = f2bf(r0);
      ob[128 + c*3 + 0] = f2bf(r1);
      ob[128 + c*3 + 1] = f2bf(r2);
      ob[128 + c*3 + 2] = f2bf(r3);
    } else {
      float* ob = (float*)outv + (size_t)b*512;
      ob[c]             = r0;
      ob[128 + c*3 + 0] = r1;
      ob[128 + c*3 + 1] = r2;
      ob[128 + c*3 + 2] = r3;
    }
  }
}

extern "C" void kernel_launch(void* const* d_in, const int* in_sizes, int n_in,
                              void* d_out, int out_size, void* d_ws, size_t ws_size,
                              hipStream_t stream) {
  int* ws = (int*)d_ws;
  hipLaunchKernelGGL(k_classify2, dim3(1), dim3(1024), 0, stream, d_in[1], ws);

  if (ws_size >= WS_NEEDED_NEW){
    u16*   ftb  = (u16*)((char*)d_ws + TBL_OFF);      // bf16 path (frag layout)
    float* tb   = (float*)((char*)d_ws + TBL_OFF);    // f32 path (SLOT layout) - exclusive
    float* part = (float*)((char*)d_ws + PART_OFF);

    // bf16 pipeline (self-gated on ws[15])
    hipLaunchKernelGGL(k_buildF, dim3(36, 8, 10), dim3(64), 0, stream,
                       d_in[2], d_in[3], d_in[4], d_in[5], d_in[6], d_in[7],
                       d_in[8], d_in[9], d_in[10], d_in[11], d_in[12], d_in[13],
                       ws, ftb);
    hipLaunchKernelGGL(k_contract_mfma, dim3(1280, 2), dim3(64), 0, stream,
                       (const u16*)d_in[0], ws, ftb, (u16*)d_out);

    // f32 pipeline (self-gated on !ws[15])
    hipLaunchKernelGGL(k_build3, dim3(73, 16, 10), dim3(128), 0, stream,
                       d_in[2], d_in[3], d_in[4], d_in[5], d_in[6], d_in[7],
                       d_in[8], d_in[9], d_in[10], d_in[11], d_in[12], d_in[13],
                       ws, tb);
    hipLaunchKernelGGL(k_contract3, dim3(1280, 4), dim3(TPB), 0, stream,
                       d_in[0], ws, tb, part);
    hipLaunchKernelGGL(k_combine, dim3(1024), dim3(128), 0, stream,
                       part, ws, d_out);
  } else {
    hipLaunchKernelGGL(k_contract, dim3(1280), dim3(TPB), 0, stream,
                       d_in[0],
                       d_in[2], d_in[3], d_in[4], d_in[5], d_in[6], d_in[7],
                       d_in[8], d_in[9], d_in[10], d_in[11], d_in[12], d_in[13],
                       ws, d_out);
  }
}

// Round 9
// 157.706 us; speedup vs baseline: 1.1449x; 1.0510x over previous
//
#include <hip/hip_runtime.h>
#include <hip/hip_bf16.h>

typedef unsigned short u16;
typedef __attribute__((ext_vector_type(8))) short bf16x8;   // MFMA A/B frag (8 bf16)
typedef __attribute__((ext_vector_type(4))) float f32x4;

// ws layout: ints ws[0..9]=counts, ws[16+e*1024+j]=atom lists (f32 committed; no dtype flag).
// MFMA tables at TBL_OFF:
//   ftm: bf16 A-frag halves [(ec*36+t)*2+hl][lane<32][8]   (47.2 MB)
//   fta2: f32 A2 bias      [ec*36+t][row16]                ( 2.9 MB)
#define TBL_OFF 65536
#define FT_BYTES ((size_t)1280*36*2*512)
#define A2_OFF (TBL_OFF + FT_BYTES)
#define A2_BYTES ((size_t)1280*36*16*4)
#define WS_NEEDED_MFMA (A2_OFF + A2_BYTES)   // ~50.2 MB (known available: >=64.6 MB)

__device__ __forceinline__ float bf2f(u16 v){
  union { unsigned int u; float f; } x; x.u = ((unsigned int)v) << 16; return x.f;
}
__device__ __forceinline__ u16 f2bf(float f){
  union { float f; unsigned int u; } x; x.f = f;
  unsigned int u = x.u;
  u += 0x7FFFu + ((u >> 16) & 1u);   // round-to-nearest-even
  return (u16)(u >> 16);
}

// ============ kernel 1: per-species atom lists (f32 one-hot) =================
__global__ void k_classify(const float* __restrict__ na, int* __restrict__ ws){
  __shared__ int scnt[10];
  const int b = threadIdx.x;  // 1024 threads
  if (b < 10) scnt[b] = 0;
  __syncthreads();
  int e = 0;
  #pragma unroll
  for (int j = 0; j < 10; j++){
    if (na[b*10 + j] > 0.5f) e = j;
  }
  int pos = atomicAdd(&scnt[e], 1);   // per-atom outputs are order-independent
  ws[16 + e*1024 + pos] = b;
  __syncthreads();
  if (b < 10) ws[b] = scnt[b];
}

// ============ kernel B: build packed A-frag table (hi/lo bf16) ===============
// A3ext rows: p<136 folded-sym A3 (k<16) + A2 bias (k=16, stored separately);
// p==136 = A1 row; p 137..143 = 0.  Tile t = q*9+pb, rows pb*16..+15.
// ftm stores only k<16 half: lane l<32 holds row (l&15), k=(l>>4)*8+j.
// grid (36 t, 8 cgroups of 16, 10 e), block 64
__global__ __launch_bounds__(64) void k_buildF2(
    const float* __restrict__ U3_0, const float* __restrict__ U2_0, const float* __restrict__ U1_0,
    const float* __restrict__ W3_0, const float* __restrict__ W2_0, const float* __restrict__ W1_0,
    const float* __restrict__ U3_1, const float* __restrict__ U2_1, const float* __restrict__ U1_1,
    const float* __restrict__ W3_1, const float* __restrict__ W2_1, const float* __restrict__ W1_1,
    u16* __restrict__ ftm, float* __restrict__ fta2)
{
  const int t  = blockIdx.x;         // 0..35
  const int cg = blockIdx.y;         // 0..7
  const int e  = blockIdx.z;         // 0..9
  const int q  = t / 9, pb = t % 9;
  const int lane = threadIdx.x;
  const int g = lane >> 4, row = lane & 15;
  const int p = pb*16 + row;
  const int c0 = cg*16;

  // W slots: 0-4 W3_0 | 5-11 W3_1 | 12-13 W2_0 | 14-16 W2_1 | 17 W1_0 | 18 W1_1
  __shared__ float sW[19*16];
  for (int idx = lane; idx < 304; idx += 64){   // strided: 304 > blockDim
    const int slot = idx >> 4, cc = idx & 15;
    const int c = c0 + cc;
    float v;
    if      (slot < 5)  v = W3_0[(e*5 + slot)*128 + c];
    else if (slot < 12) v = W3_1[(e*7 + slot - 5)*128 + c];
    else if (slot < 14) v = W2_0[(e*2 + slot - 12)*128 + c];
    else if (slot < 17) v = W2_1[(e*3 + slot - 14)*128 + c];
    else if (slot == 17) v = W1_0[e*128 + c];
    else                 v = W1_1[e*128 + c];
    sW[slot*16 + cc] = v;
  }
  __syncthreads();

  float u[8][7];
  #pragma unroll
  for (int j = 0; j < 8; j++)
    #pragma unroll
    for (int k = 0; k < 7; k++) u[j][k] = 0.f;
  int K = 0, slot0 = 0;
  float a2u[3] = {0.f, 0.f, 0.f};
  int a2K = 0, a2slot = 12;

  if (p < 136){
    int i1 = 0, rem = p;
    while (rem >= 16 - i1){ rem -= 16 - i1; i1++; }
    const int i2 = i1 + rem;
    if (g < 2){
      if (q == 0){
        K = 5; slot0 = 0;
        #pragma unroll
        for (int j = 0; j < 8; j++){
          const int i3 = g*8 + j;
          const int a  = (i1*256 + i2*16 + i3)*5;
          const int bb = (i2*256 + i1*16 + i3)*5;
          #pragma unroll
          for (int k = 0; k < 5; k++){
            float v = U3_0[a + k];
            if (i1 != i2) v += U3_0[bb + k];
            u[j][k] = v;
          }
        }
      } else {
        K = 7; slot0 = 5;
        const int mm = q - 1;
        #pragma unroll
        for (int j = 0; j < 8; j++){
          const int i3 = g*8 + j;
          const int a  = (mm*4096 + i1*256 + i2*16 + i3)*7;
          const int bb = (mm*4096 + i2*256 + i1*16 + i3)*7;
          #pragma unroll
          for (int k = 0; k < 7; k++){
            float v = U3_1[a + k];
            if (i1 != i2) v += U3_1[bb + k];
            u[j][k] = v;
          }
        }
      }
    } else if (g == 2){
      if (q == 0){
        a2K = 2; a2slot = 12;
        const int a = (i1*16 + i2)*2, bb = (i2*16 + i1)*2;
        #pragma unroll
        for (int k = 0; k < 2; k++){
          float v = U2_0[a + k];
          if (i1 != i2) v += U2_0[bb + k];
          a2u[k] = v;
        }
      } else {
        a2K = 3; a2slot = 14;
        const int mm = q - 1;
        const int a = (mm*256 + i1*16 + i2)*3, bb = (mm*256 + i2*16 + i1)*3;
        #pragma unroll
        for (int k = 0; k < 3; k++){
          float v = U2_1[a + k];
          if (i1 != i2) v += U2_1[bb + k];
          a2u[k] = v;
        }
      }
    }
  } else if (p == 136 && g < 2){
    K = 1; slot0 = (q == 0) ? 17 : 18;
    #pragma unroll
    for (int j = 0; j < 8; j++){
      const int i = g*8 + j;
      u[j][0] = (q == 0) ? U1_0[i] : U1_1[(q - 1)*16 + i];
    }
  }
  // p>136 or other lanes: zeros

  for (int cc = 0; cc < 16; cc++){
    const int ec = e*128 + c0 + cc;
    if (g < 2){
      bf16x8 vh, vl;
      #pragma unroll
      for (int j = 0; j < 8; j++){
        float v = 0.f;
        #pragma unroll
        for (int k = 0; k < 7; k++)
          if (k < K) v += u[j][k] * sW[(slot0 + k)*16 + cc];
        u16 h = f2bf(v);
        vh[j] = (short)h;
        vl[j] = (short)f2bf(v - bf2f(h));
      }
      u16* dp = ftm + (((size_t)ec*36 + t)*2)*256 + lane*8;
      *(bf16x8*)dp         = vh;
      *(bf16x8*)(dp + 256) = vl;
    } else if (g == 2){
      float v = 0.f;
      #pragma unroll
      for (int k = 0; k < 3; k++)
        if (k < a2K) v += a2u[k] * sW[(a2slot + k)*16 + cc];
      fta2[((size_t)ec*36 + t)*16 + row] = v;   // zero for p>=136 (a2K=0)
    }
    // g==3: nothing stored (reconstructed as zeros at load)
  }
}

// ============ kernel C: MFMA contraction with hi/lo split ====================
// grid (1280 ec, 2 qpair), block 64 (1 wave).
// D[row=p (lane>>4)*4+reg][col=atom lane&15]; out[q] = sum_p m_p * D[p].
__global__ __launch_bounds__(64) void k_cmfma(
    const float* __restrict__ x, const int* __restrict__ ws,
    const u16* __restrict__ ftm, const float* __restrict__ fta2,
    float* __restrict__ out)
{
  const int e = blockIdx.x >> 7, c = blockIdx.x & 127;
  const int qp = blockIdx.y;
  const int lane = threadIdx.x;
  const int count = ws[e];
  if (count == 0) return;
  const int* lst = ws + 16 + e*1024;
  const int col = lane & 15, g = lane >> 4;
  const size_t ec = (size_t)(e*128 + c);

  __shared__ float sx[16][20];   // [col][i]; [16]=1.0 (A1 row), [17..19]=0 (pads)
  __shared__ int   sip[144];     // p -> i1 | i2<<8

  for (int p = lane; p < 144; p += 64){
    int i1, i2;
    if (p < 136){ int a = 0, r = p; while (r >= 16 - a){ r -= 16 - a; a++; } i1 = a; i2 = a + r; }
    else if (p == 136){ i1 = 16; i2 = 16; }
    else { i1 = 17; i2 = 17; }
    sip[p] = i1 | (i2 << 8);
  }
  if (lane < 16){ sx[lane][16] = 1.f; sx[lane][17] = 0.f; sx[lane][18] = 0.f; sx[lane][19] = 0.f; }
  __syncthreads();

  // A-frags for this block's 2 q's (18 tiles x hi/lo), pinned in VGPRs
  bf16x8 ah[18], al[18];
  #pragma unroll
  for (int i = 0; i < 18; i++){
    const int t = qp*18 + i;
    if (g < 2){
      const u16* fp = ftm + ((ec*36 + t)*2)*256 + lane*8;
      ah[i] = *(const bf16x8*)fp;
      al[i] = *(const bf16x8*)(fp + 256);
    } else if (g == 2){
      // bias column k=16 (j==0): A2 value
      float a2 = fta2[(ec*36 + t)*16 + col];
      u16 h = f2bf(a2);
      float lo = a2 - bf2f(h);
      bf16x8 z = (bf16x8){0,0,0,0,0,0,0,0};
      z[0] = (short)h;        ah[i] = z;
      z[0] = (short)f2bf(lo); al[i] = z;
    } else {
      ah[i] = (bf16x8){0,0,0,0,0,0,0,0};
      al[i] = (bf16x8){0,0,0,0,0,0,0,0};
    }
  }

  const int ngr = (count + 15) >> 4;
  for (int grp = 0; grp < ngr; grp++){
    const int aidx = grp*16 + col;
    const bool act = aidx < count;
    const int b = lst[act ? aidx : count - 1];   // clamp; store-masked

    // B-frag: col=atom, k=g*8+j.  g<2: x hi/lo; g==2 j==0: 1.0 (bias); else 0
    bf16x8 bh = (bf16x8){0,0,0,0,0,0,0,0};
    bf16x8 bl = (bf16x8){0,0,0,0,0,0,0,0};
    if (g < 2){
      const float* xp = x + ((size_t)b*128 + c)*16 + g*8;
      f32x4 v0 = *(const f32x4*)xp;
      f32x4 v1 = *(const f32x4*)(xp + 4);
      float xv[8];
      #pragma unroll
      for (int j = 0; j < 4; j++){ xv[j] = v0[j]; xv[4 + j] = v1[j]; }
      #pragma unroll
      for (int j = 0; j < 8; j++){
        u16 h = f2bf(xv[j]);
        bh[j] = (short)h;
        bl[j] = (short)f2bf(xv[j] - bf2f(h));
        sx[col][g*8 + j] = xv[j];
      }
    } else if (g == 2){
      bh[0] = (short)0x3F80;   // 1.0 bf16; x_lo of bias col = 0
    }
    __syncthreads();

    float r0 = 0.f, r1 = 0.f;
    #pragma unroll
    for (int pb = 0; pb < 9; pb++){
      f32x4 acc0 = {0.f, 0.f, 0.f, 0.f};
      f32x4 acc1 = {0.f, 0.f, 0.f, 0.f};
      acc0 = __builtin_amdgcn_mfma_f32_16x16x32_bf16(ah[pb],     bh, acc0, 0, 0, 0);
      acc0 = __builtin_amdgcn_mfma_f32_16x16x32_bf16(ah[pb],     bl, acc0, 0, 0, 0);
      acc0 = __builtin_amdgcn_mfma_f32_16x16x32_bf16(al[pb],     bh, acc0, 0, 0, 0);
      acc1 = __builtin_amdgcn_mfma_f32_16x16x32_bf16(ah[9 + pb], bh, acc1, 0, 0, 0);
      acc1 = __builtin_amdgcn_mfma_f32_16x16x32_bf16(ah[9 + pb], bl, acc1, 0, 0, 0);
      acc1 = __builtin_amdgcn_mfma_f32_16x16x32_bf16(al[9 + pb], bh, acc1, 0, 0, 0);
      float m[4];
      #pragma unroll
      for (int r = 0; r < 4; r++){
        const int ip = sip[pb*16 + g*4 + r];
        m[r] = sx[col][ip & 0xff] * sx[col][ip >> 8];
      }
      r0 += m[0]*acc0[0] + m[1]*acc0[1] + m[2]*acc0[2] + m[3]*acc0[3];
      r1 += m[0]*acc1[0] + m[1]*acc1[1] + m[2]*acc1[2] + m[3]*acc1[3];
    }
    // reduce row-quarters across the 4 lane groups
    r0 += __shfl_xor(r0, 16); r0 += __shfl_xor(r0, 32);
    r1 += __shfl_xor(r1, 16); r1 += __shfl_xor(r1, 32);

    if (act && g == 0){
      float* ob = out + (size_t)b*512;
      if (qp == 0){ ob[c] = r0;               ob[128 + c*3 + 0] = r1; }
      else        { ob[128 + c*3 + 1] = r0;   ob[128 + c*3 + 2] = r1; }
    }
    __syncthreads();   // protect sx before next group's overwrite
  }
}

// ===================== tiny-ws fallback (round-3 structure, f32) =============
__global__ __launch_bounds__(128) void k_contract_f32(
    const float* __restrict__ a_i,
    const float* __restrict__ U3_0, const float* __restrict__ U2_0, const float* __restrict__ U1_0,
    const float* __restrict__ W3_0, const float* __restrict__ W2_0, const float* __restrict__ W1_0,
    const float* __restrict__ U3_1, const float* __restrict__ U2_1, const float* __restrict__ U1_1,
    const float* __restrict__ W3_1, const float* __restrict__ W2_1, const float* __restrict__ W1_1,
    const int* __restrict__ ws, float* __restrict__ outv)
{
  const int bx  = blockIdx.x;
  const int e   = bx >> 7;
  const int c   = bx & 127;
  const int tid = threadIdx.x;

  __shared__ float sA3[4*136*16];
  __shared__ float sA2[4*136];
  __shared__ float sA1[4*16];
  __shared__ unsigned char sI1[136], sI2[136];
  __shared__ float sX[128][17];

  for (int p = tid; p < 136; p += 128){
    int i1 = 0, rem = p;
    while (rem >= 16 - i1){ rem -= 16 - i1; i1++; }
    sI1[p] = (unsigned char)i1;
    sI2[p] = (unsigned char)(i1 + rem);
  }

  float w3_0[5], w2_0[2], w3_1[7], w2_1[3];
  #pragma unroll
  for (int k = 0; k < 5; k++) w3_0[k] = W3_0[(e*5 + k)*128 + c];
  #pragma unroll
  for (int k = 0; k < 2; k++) w2_0[k] = W2_0[(e*2 + k)*128 + c];
  const float w1_0 = W1_0[e*128 + c];
  #pragma unroll
  for (int k = 0; k < 7; k++) w3_1[k] = W3_1[(e*7 + k)*128 + c];
  #pragma unroll
  for (int k = 0; k < 3; k++) w2_1[k] = W2_1[(e*3 + k)*128 + c];
  const float w1_1 = W1_1[e*128 + c];

  __syncthreads();

  for (int q = 0; q < 4; q++){
    for (int idx = tid; idx < 136*16; idx += 128){
      const int p  = idx >> 4;
      const int i3 = idx & 15;
      const int i1 = sI1[p], i2 = sI2[p];
      float v = 0.f;
      if (q == 0){
        const int a  = (i1*256 + i2*16 + i3)*5;
        const int bb = (i2*256 + i1*16 + i3)*5;
        #pragma unroll
        for (int k = 0; k < 5; k++){
          float u = U3_0[a + k];
          if (i1 != i2) u += U3_0[bb + k];
          v += u * w3_0[k];
        }
      } else {
        const int m  = q - 1;
        const int a  = (m*4096 + i1*256 + i2*16 + i3)*7;
        const int bb = (m*4096 + i2*256 + i1*16 + i3)*7;
        #pragma unroll
        for (int k = 0; k < 7; k++){
          float u = U3_1[a + k];
          if (i1 != i2) u += U3_1[bb + k];
          v += u * w3_1[k];
        }
      }
      sA3[q*2176 + idx] = v;
    }
  }
  for (int idx = tid; idx < 4*136; idx += 128){
    const int q = idx / 136, p = idx - q*136;
    const int i1 = sI1[p], i2 = sI2[p];
    float v = 0.f;
    if (q == 0){
      const int a = (i1*16 + i2)*2, bb = (i2*16 + i1)*2;
      #pragma unroll
      for (int k = 0; k < 2; k++){
        float u = U2_0[a + k];
        if (i1 != i2) u += U2_0[bb + k];
        v += u * w2_0[k];
      }
    } else {
      const int m = q - 1;
      const int a = (m*256 + i1*16 + i2)*3, bb = (m*256 + i2*16 + i1)*3;
      #pragma unroll
      for (int k = 0; k < 3; k++){
        float u = U2_1[a + k];
        if (i1 != i2) u += U2_1[bb + k];
        v += u * w2_1[k];
      }
    }
    sA2[idx] = v;
  }
  if (tid < 64){
    const int q = tid >> 4, i1 = tid & 15;
    sA1[tid] = (q == 0) ? U1_0[i1] * w1_0 : U1_1[(q - 1)*16 + i1] * w1_1;
  }
  __syncthreads();

  const int count = ws[e];
  const int* lst  = ws + 16 + e*1024;

  for (int t = tid; t < count; t += 128){
    const int b = lst[t];
    const float* xp = a_i + (size_t)(b*128 + c)*16;
    float xr[16];
    #pragma unroll
    for (int i = 0; i < 16; i++) xr[i] = xp[i];
    #pragma unroll
    for (int i = 0; i < 16; i++) sX[tid][i] = xr[i];

    float r0 = 0.f, r1 = 0.f, r2 = 0.f, r3 = 0.f;
    int p = 0;
    for (int i1 = 0; i1 < 16; i1++){
      const float x1 = sX[tid][i1];
      for (int i2 = i1; i2 < 16; i2++, p++){
        const float* a0 = &sA3[(0*136 + p)*16];
        const float* a1 = &sA3[(1*136 + p)*16];
        const float* a2 = &sA3[(2*136 + p)*16];
        const float* a3 = &sA3[(3*136 + p)*16];
        float s0 = sA2[p], s1 = sA2[136 + p], s2 = sA2[272 + p], s3 = sA2[408 + p];
        #pragma unroll
        for (int i3 = 0; i3 < 16; i3++){
          const float xv = xr[i3];
          s0 += a0[i3]*xv; s1 += a1[i3]*xv; s2 += a2[i3]*xv; s3 += a3[i3]*xv;
        }
        const float xx = x1 * sX[tid][i2];
        r0 += s0*xx; r1 += s1*xx; r2 += s2*xx; r3 += s3*xx;
      }
    }
    #pragma unroll
    for (int i1 = 0; i1 < 16; i1++){
      const float xv = xr[i1];
      r0 += sA1[i1]*xv; r1 += sA1[16 + i1]*xv; r2 += sA1[32 + i1]*xv; r3 += sA1[48 + i1]*xv;
    }

    float* ob = outv + (size_t)b*512;
    ob[c]             = r0;
    ob[128 + c*3 + 0] = r1;
    ob[128 + c*3 + 1] = r2;
    ob[128 + c*3 + 2] = r3;
  }
}

extern "C" void kernel_launch(void* const* d_in, const int* in_sizes, int n_in,
                              void* d_out, int out_size, void* d_ws, size_t ws_size,
                              hipStream_t stream) {
  int* ws = (int*)d_ws;
  hipLaunchKernelGGL(k_classify, dim3(1), dim3(1024), 0, stream,
                     (const float*)d_in[1], ws);

  if (ws_size >= WS_NEEDED_MFMA){
    u16*   ftm  = (u16*)((char*)d_ws + TBL_OFF);
    float* fta2 = (float*)((char*)d_ws + A2_OFF);
    hipLaunchKernelGGL(k_buildF2, dim3(36, 8, 10), dim3(64), 0, stream,
                       (const float*)d_in[2], (const float*)d_in[3], (const float*)d_in[4],
                       (const float*)d_in[5], (const float*)d_in[6], (const float*)d_in[7],
                       (const float*)d_in[8], (const float*)d_in[9], (const float*)d_in[10],
                       (const float*)d_in[11], (const float*)d_in[12], (const float*)d_in[13],
                       ftm, fta2);
    hipLaunchKernelGGL(k_cmfma, dim3(1280, 2), dim3(64), 0, stream,
                       (const float*)d_in[0], ws, ftm, fta2, (float*)d_out);
  } else {
    hipLaunchKernelGGL(k_contract_f32, dim3(1280), dim3(128), 0, stream,
                       (const float*)d_in[0],
                       (const float*)d_in[2], (const float*)d_in[3], (const float*)d_in[4],
                       (const float*)d_in[5], (const float*)d_in[6], (const float*)d_in[7],
                       (const float*)d_in[8], (const float*)d_in[9], (const float*)d_in[10],
                       (const float*)d_in[11], (const float*)d_in[12], (const float*)d_in[13],
                       ws, (float*)d_out);
  }
}